// Round 17
// baseline (105.599 us; speedup 1.0000x reference)
//
#include <hip/hip_runtime.h>

// GaussianActionField: out[b][k][y] = sum_n exp(-(x[b]·P[n,:,k] - posP[n][k])^2 / (2 s^2)) * color[n][y]
// B=256 N=65536 XD=32 YD=64 K=8.
// Dense attention-style (R13 math, verified; R14 = conflict-free LDS layouts only):
//   screen GEMM (swapped: S^T = P·x, exact 2x2 bf16 split, 4 MFMA) -> in-register exp2
//   -> cvt_pk bf16 -> PV GEMM (out^T += color^T · G) at full K=32.
//   sPb layout [ks=k*2+s][lane][8]: wave fragment reads are 1 KB contiguous (0 conflicts).
//   rawP padded 65 float4/n + bijective staging remap: DMA-read pairs and sPb writes
//   both bank-uniform. sCol staged row-wise via b64 writes (~2-way).
//   P DMA'd via global_load_lds (0 VGPR) during compute; XCD sibling swizzle for L2.
// gaf_pre: meta[n][k] = (posP, -log2e/(2 s^2)) table (4 MB in ws).
// gaf_reduce: out = sum over NR partials.

typedef __attribute__((ext_vector_type(8))) short short8;
typedef __attribute__((ext_vector_type(4))) float f32x4;

#define NTOT   65536
#define XD     32
#define YD     64
#define KK     8
#define META_BYTES (NTOT*KK*8)     // float2 per (n,k) = 4 MB
#define PART_FLOATS 32768          // per block: 64b x 8k x 64y
#define NCHUNKS 2048               // 32-n chunks
#define CSTR   40                  // sCol row stride (u16)

__device__ __forceinline__ void gload16(const void* g, void* l) {
  __builtin_amdgcn_global_load_lds(
      (const __attribute__((address_space(1))) unsigned*)g,
      (__attribute__((address_space(3))) unsigned*)l, 16, 0, 0);
}

union FragU { unsigned u[4]; short8 s8; };

// ---------------- pre: posP + exponent scale table ----------------
__global__ __launch_bounds__(256)
void gaf_pre(const float* __restrict__ pos, const float* __restrict__ proj,
             const float* __restrict__ sig, float2* __restrict__ meta) {
  int gid = blockIdx.x * 256 + threadIdx.x;    // (n,k) flat
  int n = gid >> 3, k = gid & 7;
  const float*  pk = proj + (size_t)n * XD * KK + k;
  const float4* pg = (const float4*)(pos + (size_t)n * XD);
  float d = 0.f;
#pragma unroll
  for (int j = 0; j < 8; ++j) {
    float4 v = pg[j];
    d = fmaf(v.x, pk[(4*j+0)*KK], d);
    d = fmaf(v.y, pk[(4*j+1)*KK], d);
    d = fmaf(v.z, pk[(4*j+2)*KK], d);
    d = fmaf(v.w, pk[(4*j+3)*KK], d);
  }
  float s = sig[gid];
  meta[gid] = make_float2(d, -0.72134752044448169f / (s * s));
}

// ---------------- main: dense screen->exp->PV, register-fused ----------------
__global__ __launch_bounds__(512, 4)
void gaf_main(const float* __restrict__ x, const float* __restrict__ proj,
              const float* __restrict__ colr, const float2* __restrict__ meta,
              float* __restrict__ partial, int NCH, int NR) {
  // pool: sPb0[16][512] u16 (16KB) | sPb1[16][512] u16 (16KB) | sCol[64][40] u16 (5120B)
  __shared__ __align__(16) unsigned short sPool[16*512*2 + 64*CSTR];   // 37888 B
  __shared__ float sPosP[8][36];
  __shared__ float sInv[8][36];
  __shared__ __align__(16) float rawP[32*260];         // padded: 65 float4 per n (33280 B)
  unsigned short* sPb0 = sPool;                        // [ks][l*8+j]
  unsigned short* sPb1 = sPool + 16*512;
  unsigned short (*sCol)[CSTR] = (unsigned short(*)[CSTR])(sPool + 2*16*512);

  const int t = threadIdx.x, l = t & 63, w = t >> 6;

  // ---- XCD sibling swizzle (bijective when NR%8==0) ----
  int nr, sblk;
  {
    const int gid = blockIdx.x;
    if ((NR & 7) == 0) {
      const int xcd = gid & 7, j = gid >> 3;   // consecutive gid round-robin XCDs
      nr   = xcd * (NR >> 3) + (j >> 2);       // 4 siblings share xcd
      sblk = j & 3;
    } else { nr = gid >> 2; sblk = gid & 3; }
  }

  const int bt = w & 3, k0 = (w >> 2) * 4;     // wave: b-tile bt, k's k0..k0+3
  const int lc = l & 15, lg = l >> 4;          // lane col / group
  const int cbeg = nr * NCH;
  int cend = cbeg + NCH; if (cend > NCHUNKS) cend = NCHUNKS;

  float* pb = partial + (size_t)(nr * 4 + sblk) * PART_FLOATS;   // logical slot
  if (cbeg >= cend) {                          // idle block: zero partial
    float4 z = {0.f,0.f,0.f,0.f};
#pragma unroll
    for (int r = 0; r < PART_FLOATS/4/512; ++r) ((float4*)pb)[t + r*512] = z;
    return;
  }

  // x B-fragments (2-way bf16 split), wave's b-tile: lane holds x[b=lc][i=lg*8+j]
  short8 xf0, xf1;
  {
    const int brow = sblk*64 + bt*16 + lc;
    const float4* xr = (const float4*)(x + (size_t)brow*XD + lg*8);
    float4 u0 = xr[0], u1 = xr[1];
    float xv[8] = {u0.x,u0.y,u0.z,u0.w,u1.x,u1.y,u1.z,u1.w};
#pragma unroll
    for (int j = 0; j < 8; ++j) {
      unsigned u = __float_as_uint(xv[j]);
      unsigned short h0 = (unsigned short)(u >> 16);        // trunc (exact residual)
      float r1 = xv[j] - __uint_as_float(u & 0xFFFF0000u);
      unsigned ur = __float_as_uint(r1);
      ur += 0x7FFFu + ((ur >> 16) & 1u);                    // RNE
      xf0[j] = (short)h0;
      xf1[j] = (short)(unsigned short)(ur >> 16);
    }
  }

  f32x4 acc[4][4];                             // [k-kk][y-subtile]
#pragma unroll
  for (int a = 0; a < 4; ++a)
#pragma unroll
    for (int b = 0; b < 4; ++b) acc[a][b] = (f32x4){0.f,0.f,0.f,0.f};

  // staging mapping constants (bijective thread -> (n, ip, kp))
  const int kp  = l & 1;
  const int ipL = (l >> 1) & 3;
  const int nS  = ((l >> 3) & 7) | ((w & 3) << 3);          // n = 0..31
  const int sS  = nS >> 4;
  const int ldst= (nS & 15);

  // P chunk DMA: one n per wave-instr, padded dest base n*1040 B
  auto ISSUE_P = [&](int c) {
    const float4* Pg = (const float4*)(proj + (size_t)c * 32 * XD * KK);
#pragma unroll
    for (int r2 = 0; r2 < 4; ++r2) {
      const int nd = w + r2*8;
      gload16(Pg + nd*64 + l, &rawP[nd*260]);
    }
  };

  ISSUE_P(cbeg);
  for (int c = cbeg; c < cend; ++c) {
    __syncthreads();                           // rawP[c] arrived; sPb free (compute done)
    // ---- stage chunk c ----
    // issue color (row-gather) + meta loads first; latency hides under the P-split
    const int yq = w*8 + (l>>3);               // y = 0..63
    const int nq = (l&7)*4;
    const float* cb = colr + (size_t)(c*32 + nq)*YD + yq;
    float c0 = cb[0], c1 = cb[YD], c2 = cb[2*YD], c3 = cb[3*YD];
    float2 mpf;
    if (t < 256) mpf = meta[(size_t)c * 256 + t];
    { // P 2-way split from padded rawP -> sPb[ks][l_dst][...] (all bank-uniform)
      const float4* raw4 = (const float4*)rawP;
#pragma unroll
      for (int r = 0; r < 2; ++r) {
        const int ip = ipL | (((w >> 2) & 1) << 2) | (r << 3);   // 0..15; i0 = 2*ip
        const int f0 = nS * 65 + ip * 4 + kp;
        float4 va = raw4[f0], vb = raw4[f0 + 2];
        const int l_dst = ldst | ((ip >> 2) << 4);
        const int wd = ip & 3;
        float ea[4] = {va.x, va.y, va.z, va.w};
        float eb[4] = {vb.x, vb.y, vb.z, vb.w};
#pragma unroll
        for (int jj = 0; jj < 4; ++jj) {
          const int ks = (kp*4 + jj)*2 + sS;
          unsigned hi, lo;
          asm("v_cvt_pk_bf16_f32 %0, %1, %2" : "=v"(hi) : "v"(ea[jj]), "v"(eb[jj]));
          float r0 = ea[jj] - __uint_as_float(hi << 16);          // exact residuals
          float r1 = eb[jj] - __uint_as_float(hi & 0xFFFF0000u);
          asm("v_cvt_pk_bf16_f32 %0, %1, %2" : "=v"(lo) : "v"(r0), "v"(r1));
          ((unsigned*)sPb0)[ks*256 + l_dst*4 + wd] = hi;
          ((unsigned*)sPb1)[ks*256 + l_dst*4 + wd] = lo;
        }
      }
    }
    { // colorT row-write: 2 cvt_pk -> one aligned b64 (~2-way banks)
      unsigned w0, w1;
      asm("v_cvt_pk_bf16_f32 %0, %1, %2" : "=v"(w0) : "v"(c0), "v"(c1));
      asm("v_cvt_pk_bf16_f32 %0, %1, %2" : "=v"(w1) : "v"(c2), "v"(c3));
      *(uint2*)&sCol[yq][nq] = make_uint2(w0, w1);
    }
    if (t < 256) { sPosP[t&7][t>>3] = mpf.x; sInv[t&7][t>>3] = mpf.y; }
    __syncthreads();                           // sPb ready; rawP fully consumed
    if (c + 1 < cend) ISSUE_P(c + 1);          // DMA next chunk under compute (0 VGPR)

    // ---- compute: screen (S^T) -> exp -> PV(K=32), all register-local ----
#pragma unroll
    for (int kk = 0; kk < 4; ++kk) {
      const int k = k0 + kk;
      FragU gb;
      { // s = 0 half: n = lc
        short8 p0 = *(const short8*)&sPb0[(k*2+0)*512 + l*8];    // contiguous 1KB/wave
        short8 p1 = *(const short8*)&sPb1[(k*2+0)*512 + l*8];
        f32x4 S = (f32x4){0.f,0.f,0.f,0.f};
        S = __builtin_amdgcn_mfma_f32_16x16x32_bf16(p1, xf1, S, 0, 0, 0);
        S = __builtin_amdgcn_mfma_f32_16x16x32_bf16(p1, xf0, S, 0, 0, 0);
        S = __builtin_amdgcn_mfma_f32_16x16x32_bf16(p0, xf1, S, 0, 0, 0);
        S = __builtin_amdgcn_mfma_f32_16x16x32_bf16(p0, xf0, S, 0, 0, 0);
        float4 pp = *(const float4*)&sPosP[k][lg*4];
        float4 iv = *(const float4*)&sInv[k][lg*4];
        float d0 = S[0]-pp.x, d1 = S[1]-pp.y, d2 = S[2]-pp.z, d3 = S[3]-pp.w;
        float g0 = __builtin_amdgcn_exp2f(d0*d0*iv.x);
        float g1 = __builtin_amdgcn_exp2f(d1*d1*iv.y);
        float g2 = __builtin_amdgcn_exp2f(d2*d2*iv.z);
        float g3 = __builtin_amdgcn_exp2f(d3*d3*iv.w);
        asm("v_cvt_pk_bf16_f32 %0, %1, %2" : "=v"(gb.u[0]) : "v"(g0), "v"(g1));
        asm("v_cvt_pk_bf16_f32 %0, %1, %2" : "=v"(gb.u[1]) : "v"(g2), "v"(g3));
      }
      { // s = 1 half: n = 16 + lc
        short8 p0 = *(const short8*)&sPb0[(k*2+1)*512 + l*8];
        short8 p1 = *(const short8*)&sPb1[(k*2+1)*512 + l*8];
        f32x4 S = (f32x4){0.f,0.f,0.f,0.f};
        S = __builtin_amdgcn_mfma_f32_16x16x32_bf16(p1, xf1, S, 0, 0, 0);
        S = __builtin_amdgcn_mfma_f32_16x16x32_bf16(p1, xf0, S, 0, 0, 0);
        S = __builtin_amdgcn_mfma_f32_16x16x32_bf16(p0, xf1, S, 0, 0, 0);
        S = __builtin_amdgcn_mfma_f32_16x16x32_bf16(p0, xf0, S, 0, 0, 0);
        float4 pp = *(const float4*)&sPosP[k][16 + lg*4];
        float4 iv = *(const float4*)&sInv[k][16 + lg*4];
        float d0 = S[0]-pp.x, d1 = S[1]-pp.y, d2 = S[2]-pp.z, d3 = S[3]-pp.w;
        float g0 = __builtin_amdgcn_exp2f(d0*d0*iv.x);
        float g1 = __builtin_amdgcn_exp2f(d1*d1*iv.y);
        float g2 = __builtin_amdgcn_exp2f(d2*d2*iv.z);
        float g3 = __builtin_amdgcn_exp2f(d3*d3*iv.w);
        asm("v_cvt_pk_bf16_f32 %0, %1, %2" : "=v"(gb.u[2]) : "v"(g0), "v"(g1));
        asm("v_cvt_pk_bf16_f32 %0, %1, %2" : "=v"(gb.u[3]) : "v"(g2), "v"(g3));
      }
      // PV, full K=32: B slots j=0..3 <-> n=lg*4+j (s=0), j=4..7 <-> n=16+lg*4+(j-4).
      // A (color^T) uses the same K-permutation; consistent permutation cancels in MFMA.
#pragma unroll
      for (int ys = 0; ys < 4; ++ys) {
        FragU af;
        *(uint2*)&af.u[0] = *(const uint2*)&sCol[ys*16 + lc][lg*4];
        *(uint2*)&af.u[2] = *(const uint2*)&sCol[ys*16 + lc][16 + lg*4];
        acc[kk][ys] = __builtin_amdgcn_mfma_f32_16x16x32_bf16(af.s8, gb.s8,
                                                              acc[kk][ys], 0, 0, 0);
      }
    }
  }
  __syncthreads();                             // compute done before epilogue overlay

  // ---- epilogue: transpose acc via LDS, coalesced partial write ----
  float* epi = (float*)sPool + w * (64*17);    // per-wave [64y][17] f32 (34816 B < pool)
#pragma unroll
  for (int kk = 0; kk < 4; ++kk) {
    const int k = k0 + kk;
#pragma unroll
    for (int ys = 0; ys < 4; ++ys) {
#pragma unroll
      for (int r = 0; r < 4; ++r)
        epi[(ys*16 + lg*4 + r)*17 + lc] = acc[kk][ys][r];
    }
    __syncthreads();
#pragma unroll
    for (int it = 0; it < 4; ++it) {
      int bi = it*4 + lg, y0 = lc*4;
      float4 v = { epi[(y0+0)*17 + bi], epi[(y0+1)*17 + bi],
                   epi[(y0+2)*17 + bi], epi[(y0+3)*17 + bi] };
      *(float4*)&pb[(size_t)(bt*16 + bi)*512 + k*64 + y0] = v;
    }
    __syncthreads();
  }
}

// ---------------- reduce: out = sum of NR partials ----------------
__global__ __launch_bounds__(512)
void gaf_reduce(const float* __restrict__ partial, float* __restrict__ out, int NR) {
  const int b = blockIdx.x;                    // global b
  const int s = b >> 6, bl = b & 63;
  const int t = threadIdx.x;                   // (k,y) flat 0..511
  float a0 = 0.f, a1 = 0.f, a2 = 0.f, a3 = 0.f;
  int nr = 0;
  for (; nr + 4 <= NR; nr += 4) {
    a0 += partial[(size_t)((nr+0)*4 + s)*PART_FLOATS + bl*512 + t];
    a1 += partial[(size_t)((nr+1)*4 + s)*PART_FLOATS + bl*512 + t];
    a2 += partial[(size_t)((nr+2)*4 + s)*PART_FLOATS + bl*512 + t];
    a3 += partial[(size_t)((nr+3)*4 + s)*PART_FLOATS + bl*512 + t];
  }
  for (; nr < NR; ++nr)
    a0 += partial[(size_t)(nr*4 + s)*PART_FLOATS + bl*512 + t];
  out[(size_t)b*512 + t] = (a0 + a1) + (a2 + a3);
}

extern "C" void kernel_launch(void* const* d_in, const int* in_sizes, int n_in,
                              void* d_out, int out_size, void* d_ws, size_t ws_size,
                              hipStream_t stream) {
  const float* x    = (const float*)d_in[0];
  const float* pos  = (const float*)d_in[1];
  const float* proj = (const float*)d_in[2];
  const float* colr = (const float*)d_in[3];
  const float* sig  = (const float*)d_in[4];
  float* out = (float*)d_out;

  float2* meta    = (float2*)d_ws;
  float*  partial = (float*)((char*)d_ws + META_BYTES);

  size_t avail = (ws_size > META_BYTES) ? ws_size - META_BYTES : 0;
  int NR = (int)(avail / (4ull * PART_FLOATS * 4ull));  // 512 KB per NR step
  if (NR > 128) NR = 128;
  if (NR < 1)  NR = 1;
  if (NR >= 8) NR &= ~7;                       // multiple of 8 for the XCD swizzle
  int NCH = (NCHUNKS + NR - 1) / NR;

  gaf_pre<<<(NTOT*KK)/256, 256, 0, stream>>>(pos, proj, sig, meta);
  gaf_main<<<4*NR, 512, 0, stream>>>(x, proj, colr, meta, partial, NCH, NR);
  gaf_reduce<<<256, 512, 0, stream>>>(partial, out, NR);
}

// Round 18
// 100.046 us; speedup vs baseline: 1.0555x; 1.0555x over previous
//
#include <hip/hip_runtime.h>

// GaussianActionField: out[b][k][y] = sum_n exp(-(x[b]·P[n,:,k] - posP[n][k])^2 / (2 s^2)) * color[n][y]
// B=256 N=65536 XD=32 YD=64 K=8.
// R18 = R14 (verified, 105.4 us) + s_setprio(1/0) around the compute phase ONLY.
//   Minimal bisect of R16's failure (interleave vs setprio) that doubles as T5:
//   sibling blocks on a CU are phase-offset, so raising MFMA-wave priority while the
//   other block stages/DMAs can help. Data path bitwise-identical to R14.
//   Screen: S^T = P·x exact 2x2 bf16 split (4 MFMA/half) -> exp2 -> cvt_pk -> PV K=32.
//   Conflict-free sPb [ks][lane][8]; padded rawP; global_load_lds DMA; XCD swizzle.
// gaf_pre: meta[n][k] = (posP, -log2e/(2 s^2)) table (4 MB in ws).
// gaf_reduce: out = sum over NR partials.

typedef __attribute__((ext_vector_type(8))) short short8;
typedef __attribute__((ext_vector_type(4))) float f32x4;

#define NTOT   65536
#define XD     32
#define YD     64
#define KK     8
#define META_BYTES (NTOT*KK*8)     // float2 per (n,k) = 4 MB
#define PART_FLOATS 32768          // per block: 64b x 8k x 64y
#define NCHUNKS 2048               // 32-n chunks
#define CSTR   40                  // sCol row stride (u16)

__device__ __forceinline__ void gload16(const void* g, void* l) {
  __builtin_amdgcn_global_load_lds(
      (const __attribute__((address_space(1))) unsigned*)g,
      (__attribute__((address_space(3))) unsigned*)l, 16, 0, 0);
}

union FragU { unsigned u[4]; short8 s8; };

// ---------------- pre: posP + exponent scale table ----------------
__global__ __launch_bounds__(256)
void gaf_pre(const float* __restrict__ pos, const float* __restrict__ proj,
             const float* __restrict__ sig, float2* __restrict__ meta) {
  int gid = blockIdx.x * 256 + threadIdx.x;    // (n,k) flat
  int n = gid >> 3, k = gid & 7;
  const float*  pk = proj + (size_t)n * XD * KK + k;
  const float4* pg = (const float4*)(pos + (size_t)n * XD);
  float d = 0.f;
#pragma unroll
  for (int j = 0; j < 8; ++j) {
    float4 v = pg[j];
    d = fmaf(v.x, pk[(4*j+0)*KK], d);
    d = fmaf(v.y, pk[(4*j+1)*KK], d);
    d = fmaf(v.z, pk[(4*j+2)*KK], d);
    d = fmaf(v.w, pk[(4*j+3)*KK], d);
  }
  float s = sig[gid];
  meta[gid] = make_float2(d, -0.72134752044448169f / (s * s));
}

// ---------------- main: dense screen->exp->PV, register-fused ----------------
__global__ __launch_bounds__(512, 4)
void gaf_main(const float* __restrict__ x, const float* __restrict__ proj,
              const float* __restrict__ colr, const float2* __restrict__ meta,
              float* __restrict__ partial, int NCH, int NR) {
  // pool: sPb0[16][512] u16 (16KB) | sPb1[16][512] u16 (16KB) | sCol[64][40] u16 (5120B)
  __shared__ __align__(16) unsigned short sPool[16*512*2 + 64*CSTR];   // 37888 B
  __shared__ float sPosP[8][36];
  __shared__ float sInv[8][36];
  __shared__ __align__(16) float rawP[32*260];         // padded: 65 float4 per n (33280 B)
  unsigned short* sPb0 = sPool;                        // [ks][l*8+j]
  unsigned short* sPb1 = sPool + 16*512;
  unsigned short (*sCol)[CSTR] = (unsigned short(*)[CSTR])(sPool + 2*16*512);

  const int t = threadIdx.x, l = t & 63, w = t >> 6;

  // ---- XCD sibling swizzle (bijective when NR%8==0) ----
  int nr, sblk;
  {
    const int gid = blockIdx.x;
    if ((NR & 7) == 0) {
      const int xcd = gid & 7, j = gid >> 3;   // consecutive gid round-robin XCDs
      nr   = xcd * (NR >> 3) + (j >> 2);       // 4 siblings share xcd
      sblk = j & 3;
    } else { nr = gid >> 2; sblk = gid & 3; }
  }

  const int bt = w & 3, k0 = (w >> 2) * 4;     // wave: b-tile bt, k's k0..k0+3
  const int lc = l & 15, lg = l >> 4;          // lane col / group
  const int cbeg = nr * NCH;
  int cend = cbeg + NCH; if (cend > NCHUNKS) cend = NCHUNKS;

  float* pb = partial + (size_t)(nr * 4 + sblk) * PART_FLOATS;   // logical slot
  if (cbeg >= cend) {                          // idle block: zero partial
    float4 z = {0.f,0.f,0.f,0.f};
#pragma unroll
    for (int r = 0; r < PART_FLOATS/4/512; ++r) ((float4*)pb)[t + r*512] = z;
    return;
  }

  // x B-fragments (2-way bf16 split), wave's b-tile: lane holds x[b=lc][i=lg*8+j]
  short8 xf0, xf1;
  {
    const int brow = sblk*64 + bt*16 + lc;
    const float4* xr = (const float4*)(x + (size_t)brow*XD + lg*8);
    float4 u0 = xr[0], u1 = xr[1];
    float xv[8] = {u0.x,u0.y,u0.z,u0.w,u1.x,u1.y,u1.z,u1.w};
#pragma unroll
    for (int j = 0; j < 8; ++j) {
      unsigned u = __float_as_uint(xv[j]);
      unsigned short h0 = (unsigned short)(u >> 16);        // trunc (exact residual)
      float r1 = xv[j] - __uint_as_float(u & 0xFFFF0000u);
      unsigned ur = __float_as_uint(r1);
      ur += 0x7FFFu + ((ur >> 16) & 1u);                    // RNE
      xf0[j] = (short)h0;
      xf1[j] = (short)(unsigned short)(ur >> 16);
    }
  }

  f32x4 acc[4][4];                             // [k-kk][y-subtile]
#pragma unroll
  for (int a = 0; a < 4; ++a)
#pragma unroll
    for (int b = 0; b < 4; ++b) acc[a][b] = (f32x4){0.f,0.f,0.f,0.f};

  // staging mapping constants (bijective thread -> (n, ip, kp))
  const int kp  = l & 1;
  const int ipL = (l >> 1) & 3;
  const int nS  = ((l >> 3) & 7) | ((w & 3) << 3);          // n = 0..31
  const int sS  = nS >> 4;
  const int ldst= (nS & 15);

  // P chunk DMA: one n per wave-instr, padded dest base n*1040 B
  auto ISSUE_P = [&](int c) {
    const float4* Pg = (const float4*)(proj + (size_t)c * 32 * XD * KK);
#pragma unroll
    for (int r2 = 0; r2 < 4; ++r2) {
      const int nd = w + r2*8;
      gload16(Pg + nd*64 + l, &rawP[nd*260]);
    }
  };

  ISSUE_P(cbeg);
  for (int c = cbeg; c < cend; ++c) {
    __syncthreads();                           // rawP[c] arrived; sPb free (compute done)
    // ---- stage chunk c ----
    // issue color (row-gather) + meta loads first; latency hides under the P-split
    const int yq = w*8 + (l>>3);               // y = 0..63
    const int nq = (l&7)*4;
    const float* cb = colr + (size_t)(c*32 + nq)*YD + yq;
    float c0 = cb[0], c1 = cb[YD], c2 = cb[2*YD], c3 = cb[3*YD];
    float2 mpf;
    if (t < 256) mpf = meta[(size_t)c * 256 + t];
    { // P 2-way split from padded rawP -> sPb[ks][l_dst][...] (all bank-uniform)
      const float4* raw4 = (const float4*)rawP;
#pragma unroll
      for (int r = 0; r < 2; ++r) {
        const int ip = ipL | (((w >> 2) & 1) << 2) | (r << 3);   // 0..15; i0 = 2*ip
        const int f0 = nS * 65 + ip * 4 + kp;
        float4 va = raw4[f0], vb = raw4[f0 + 2];
        const int l_dst = ldst | ((ip >> 2) << 4);
        const int wd = ip & 3;
        float ea[4] = {va.x, va.y, va.z, va.w};
        float eb[4] = {vb.x, vb.y, vb.z, vb.w};
#pragma unroll
        for (int jj = 0; jj < 4; ++jj) {
          const int ks = (kp*4 + jj)*2 + sS;
          unsigned hi, lo;
          asm("v_cvt_pk_bf16_f32 %0, %1, %2" : "=v"(hi) : "v"(ea[jj]), "v"(eb[jj]));
          float r0 = ea[jj] - __uint_as_float(hi << 16);          // exact residuals
          float r1 = eb[jj] - __uint_as_float(hi & 0xFFFF0000u);
          asm("v_cvt_pk_bf16_f32 %0, %1, %2" : "=v"(lo) : "v"(r0), "v"(r1));
          ((unsigned*)sPb0)[ks*256 + l_dst*4 + wd] = hi;
          ((unsigned*)sPb1)[ks*256 + l_dst*4 + wd] = lo;
        }
      }
    }
    { // colorT row-write: 2 cvt_pk -> one aligned b64 (~2-way banks)
      unsigned w0, w1;
      asm("v_cvt_pk_bf16_f32 %0, %1, %2" : "=v"(w0) : "v"(c0), "v"(c1));
      asm("v_cvt_pk_bf16_f32 %0, %1, %2" : "=v"(w1) : "v"(c2), "v"(c3));
      *(uint2*)&sCol[yq][nq] = make_uint2(w0, w1);
    }
    if (t < 256) { sPosP[t&7][t>>3] = mpf.x; sInv[t&7][t>>3] = mpf.y; }
    __syncthreads();                           // sPb ready; rawP fully consumed
    if (c + 1 < cend) ISSUE_P(c + 1);          // DMA next chunk under compute (0 VGPR)

    // ---- compute: screen (S^T) -> exp -> PV(K=32), all register-local ----
    __builtin_amdgcn_s_setprio(1);             // T5: favor MFMA waves vs sibling stage
#pragma unroll
    for (int kk = 0; kk < 4; ++kk) {
      const int k = k0 + kk;
      FragU gb;
      { // s = 0 half: n = lc
        short8 p0 = *(const short8*)&sPb0[(k*2+0)*512 + l*8];    // contiguous 1KB/wave
        short8 p1 = *(const short8*)&sPb1[(k*2+0)*512 + l*8];
        f32x4 S = (f32x4){0.f,0.f,0.f,0.f};
        S = __builtin_amdgcn_mfma_f32_16x16x32_bf16(p1, xf1, S, 0, 0, 0);
        S = __builtin_amdgcn_mfma_f32_16x16x32_bf16(p1, xf0, S, 0, 0, 0);
        S = __builtin_amdgcn_mfma_f32_16x16x32_bf16(p0, xf1, S, 0, 0, 0);
        S = __builtin_amdgcn_mfma_f32_16x16x32_bf16(p0, xf0, S, 0, 0, 0);
        float4 pp = *(const float4*)&sPosP[k][lg*4];
        float4 iv = *(const float4*)&sInv[k][lg*4];
        float d0 = S[0]-pp.x, d1 = S[1]-pp.y, d2 = S[2]-pp.z, d3 = S[3]-pp.w;
        float g0 = __builtin_amdgcn_exp2f(d0*d0*iv.x);
        float g1 = __builtin_amdgcn_exp2f(d1*d1*iv.y);
        float g2 = __builtin_amdgcn_exp2f(d2*d2*iv.z);
        float g3 = __builtin_amdgcn_exp2f(d3*d3*iv.w);
        asm("v_cvt_pk_bf16_f32 %0, %1, %2" : "=v"(gb.u[0]) : "v"(g0), "v"(g1));
        asm("v_cvt_pk_bf16_f32 %0, %1, %2" : "=v"(gb.u[1]) : "v"(g2), "v"(g3));
      }
      { // s = 1 half: n = 16 + lc
        short8 p0 = *(const short8*)&sPb0[(k*2+1)*512 + l*8];
        short8 p1 = *(const short8*)&sPb1[(k*2+1)*512 + l*8];
        f32x4 S = (f32x4){0.f,0.f,0.f,0.f};
        S = __builtin_amdgcn_mfma_f32_16x16x32_bf16(p1, xf1, S, 0, 0, 0);
        S = __builtin_amdgcn_mfma_f32_16x16x32_bf16(p1, xf0, S, 0, 0, 0);
        S = __builtin_amdgcn_mfma_f32_16x16x32_bf16(p0, xf1, S, 0, 0, 0);
        S = __builtin_amdgcn_mfma_f32_16x16x32_bf16(p0, xf0, S, 0, 0, 0);
        float4 pp = *(const float4*)&sPosP[k][16 + lg*4];
        float4 iv = *(const float4*)&sInv[k][16 + lg*4];
        float d0 = S[0]-pp.x, d1 = S[1]-pp.y, d2 = S[2]-pp.z, d3 = S[3]-pp.w;
        float g0 = __builtin_amdgcn_exp2f(d0*d0*iv.x);
        float g1 = __builtin_amdgcn_exp2f(d1*d1*iv.y);
        float g2 = __builtin_amdgcn_exp2f(d2*d2*iv.z);
        float g3 = __builtin_amdgcn_exp2f(d3*d3*iv.w);
        asm("v_cvt_pk_bf16_f32 %0, %1, %2" : "=v"(gb.u[2]) : "v"(g0), "v"(g1));
        asm("v_cvt_pk_bf16_f32 %0, %1, %2" : "=v"(gb.u[3]) : "v"(g2), "v"(g3));
      }
      // PV, full K=32: B slots j=0..3 <-> n=lg*4+j (s=0), j=4..7 <-> n=16+lg*4+(j-4).
      // A (color^T) uses the same K-permutation; consistent permutation cancels in MFMA.
#pragma unroll
      for (int ys = 0; ys < 4; ++ys) {
        FragU af;
        *(uint2*)&af.u[0] = *(const uint2*)&sCol[ys*16 + lc][lg*4];
        *(uint2*)&af.u[2] = *(const uint2*)&sCol[ys*16 + lc][16 + lg*4];
        acc[kk][ys] = __builtin_amdgcn_mfma_f32_16x16x32_bf16(af.s8, gb.s8,
                                                              acc[kk][ys], 0, 0, 0);
      }
    }
    __builtin_amdgcn_s_setprio(0);
  }
  __syncthreads();                             // compute done before epilogue overlay

  // ---- epilogue: transpose acc via LDS, coalesced partial write ----
  float* epi = (float*)sPool + w * (64*17);    // per-wave [64y][17] f32 (34816 B < pool)
#pragma unroll
  for (int kk = 0; kk < 4; ++kk) {
    const int k = k0 + kk;
#pragma unroll
    for (int ys = 0; ys < 4; ++ys) {
#pragma unroll
      for (int r = 0; r < 4; ++r)
        epi[(ys*16 + lg*4 + r)*17 + lc] = acc[kk][ys][r];
    }
    __syncthreads();
#pragma unroll
    for (int it = 0; it < 4; ++it) {
      int bi = it*4 + lg, y0 = lc*4;
      float4 v = { epi[(y0+0)*17 + bi], epi[(y0+1)*17 + bi],
                   epi[(y0+2)*17 + bi], epi[(y0+3)*17 + bi] };
      *(float4*)&pb[(size_t)(bt*16 + bi)*512 + k*64 + y0] = v;
    }
    __syncthreads();
  }
}

// ---------------- reduce: out = sum of NR partials ----------------
__global__ __launch_bounds__(512)
void gaf_reduce(const float* __restrict__ partial, float* __restrict__ out, int NR) {
  const int b = blockIdx.x;                    // global b
  const int s = b >> 6, bl = b & 63;
  const int t = threadIdx.x;                   // (k,y) flat 0..511
  float a0 = 0.f, a1 = 0.f, a2 = 0.f, a3 = 0.f;
  int nr = 0;
  for (; nr + 4 <= NR; nr += 4) {
    a0 += partial[(size_t)((nr+0)*4 + s)*PART_FLOATS + bl*512 + t];
    a1 += partial[(size_t)((nr+1)*4 + s)*PART_FLOATS + bl*512 + t];
    a2 += partial[(size_t)((nr+2)*4 + s)*PART_FLOATS + bl*512 + t];
    a3 += partial[(size_t)((nr+3)*4 + s)*PART_FLOATS + bl*512 + t];
  }
  for (; nr < NR; ++nr)
    a0 += partial[(size_t)(nr*4 + s)*PART_FLOATS + bl*512 + t];
  out[(size_t)b*512 + t] = (a0 + a1) + (a2 + a3);
}

extern "C" void kernel_launch(void* const* d_in, const int* in_sizes, int n_in,
                              void* d_out, int out_size, void* d_ws, size_t ws_size,
                              hipStream_t stream) {
  const float* x    = (const float*)d_in[0];
  const float* pos  = (const float*)d_in[1];
  const float* proj = (const float*)d_in[2];
  const float* colr = (const float*)d_in[3];
  const float* sig  = (const float*)d_in[4];
  float* out = (float*)d_out;

  float2* meta    = (float2*)d_ws;
  float*  partial = (float*)((char*)d_ws + META_BYTES);

  size_t avail = (ws_size > META_BYTES) ? ws_size - META_BYTES : 0;
  int NR = (int)(avail / (4ull * PART_FLOATS * 4ull));  // 512 KB per NR step
  if (NR > 128) NR = 128;
  if (NR < 1)  NR = 1;
  if (NR >= 8) NR &= ~7;                       // multiple of 8 for the XCD swizzle
  int NCH = (NCHUNKS + NR - 1) / NR;

  gaf_pre<<<(NTOT*KK)/256, 256, 0, stream>>>(pos, proj, sig, meta);
  gaf_main<<<4*NR, 512, 0, stream>>>(x, proj, colr, meta, partial, NCH, NR);
  gaf_reduce<<<256, 512, 0, stream>>>(partial, out, NR);
}

// Round 19
// 99.669 us; speedup vs baseline: 1.0595x; 1.0038x over previous
//
#include <hip/hip_runtime.h>

// GaussianActionField: out[b][k][y] = sum_n exp(-(x[b]·P[n,:,k] - posP[n][k])^2 / (2 s^2)) * color[n][y]
// B=256 N=65536 XD=32 YD=64 K=8.
// R19 = R18 (verified, 100.0 us) + gaf_pre folded into gaf_main's stage phase:
//   posP/inv computed per chunk from the fp32 rawP already in LDS (bitwise-identical
//   fmaf order to the old gaf_pre) + pos chunk DMA'd via global_load_lds with a
//   src-swizzled [i4][n] layout (bank-spread reads, 0 VGPR). meta table eliminated.
//   Screen: S^T = P·x exact 2x2 bf16 split (4 MFMA/half) -> exp2 -> cvt_pk -> PV K=32.
//   Conflict-free sPb [ks][lane][8]; padded rawP; s_setprio(1) compute (T5); XCD swizzle.
// gaf_reduce: out = sum over NR partials.

typedef __attribute__((ext_vector_type(8))) short short8;
typedef __attribute__((ext_vector_type(4))) float f32x4;

#define NTOT   65536
#define XD     32
#define YD     64
#define KK     8
#define PART_FLOATS 32768          // per block: 64b x 8k x 64y
#define NCHUNKS 2048               // 32-n chunks
#define CSTR   40                  // sCol row stride (u16)

__device__ __forceinline__ void gload16(const void* g, void* l) {
  __builtin_amdgcn_global_load_lds(
      (const __attribute__((address_space(1))) unsigned*)g,
      (__attribute__((address_space(3))) unsigned*)l, 16, 0, 0);
}

union FragU { unsigned u[4]; short8 s8; };

// ---------------- main: dense screen->exp->PV, register-fused ----------------
__global__ __launch_bounds__(512, 4)
void gaf_main(const float* __restrict__ x, const float* __restrict__ pos,
              const float* __restrict__ proj, const float* __restrict__ colr,
              const float* __restrict__ sig,
              float* __restrict__ partial, int NCH, int NR) {
  // pool: sPb0[16][512] u16 (16KB) | sPb1[16][512] u16 (16KB) | sCol[64][40] u16 (5120B)
  __shared__ __align__(16) unsigned short sPool[16*512*2 + 64*CSTR];   // 37888 B
  __shared__ float sPosP[8][36];
  __shared__ float sInv[8][36];
  __shared__ __align__(16) float rawP[32*260];         // padded: 65 float4 per n (33280 B)
  __shared__ __align__(16) float rawPos[32*32];        // pos chunk, [i4][n] float4s (4096 B)
  unsigned short* sPb0 = sPool;                        // [ks][l*8+j]
  unsigned short* sPb1 = sPool + 16*512;
  unsigned short (*sCol)[CSTR] = (unsigned short(*)[CSTR])(sPool + 2*16*512);

  const int t = threadIdx.x, l = t & 63, w = t >> 6;

  // ---- XCD sibling swizzle (bijective when NR%8==0) ----
  int nr, sblk;
  {
    const int gid = blockIdx.x;
    if ((NR & 7) == 0) {
      const int xcd = gid & 7, j = gid >> 3;   // consecutive gid round-robin XCDs
      nr   = xcd * (NR >> 3) + (j >> 2);       // 4 siblings share xcd
      sblk = j & 3;
    } else { nr = gid >> 2; sblk = gid & 3; }
  }

  const int bt = w & 3, k0 = (w >> 2) * 4;     // wave: b-tile bt, k's k0..k0+3
  const int lc = l & 15, lg = l >> 4;          // lane col / group
  const int cbeg = nr * NCH;
  int cend = cbeg + NCH; if (cend > NCHUNKS) cend = NCHUNKS;

  float* pb = partial + (size_t)(nr * 4 + sblk) * PART_FLOATS;   // logical slot
  if (cbeg >= cend) {                          // idle block: zero partial
    float4 z = {0.f,0.f,0.f,0.f};
#pragma unroll
    for (int r = 0; r < PART_FLOATS/4/512; ++r) ((float4*)pb)[t + r*512] = z;
    return;
  }

  // x B-fragments (2-way bf16 split), wave's b-tile: lane holds x[b=lc][i=lg*8+j]
  short8 xf0, xf1;
  {
    const int brow = sblk*64 + bt*16 + lc;
    const float4* xr = (const float4*)(x + (size_t)brow*XD + lg*8);
    float4 u0 = xr[0], u1 = xr[1];
    float xv[8] = {u0.x,u0.y,u0.z,u0.w,u1.x,u1.y,u1.z,u1.w};
#pragma unroll
    for (int j = 0; j < 8; ++j) {
      unsigned u = __float_as_uint(xv[j]);
      unsigned short h0 = (unsigned short)(u >> 16);        // trunc (exact residual)
      float r1 = xv[j] - __uint_as_float(u & 0xFFFF0000u);
      unsigned ur = __float_as_uint(r1);
      ur += 0x7FFFu + ((ur >> 16) & 1u);                    // RNE
      xf0[j] = (short)h0;
      xf1[j] = (short)(unsigned short)(ur >> 16);
    }
  }

  f32x4 acc[4][4];                             // [k-kk][y-subtile]
#pragma unroll
  for (int a = 0; a < 4; ++a)
#pragma unroll
    for (int b = 0; b < 4; ++b) acc[a][b] = (f32x4){0.f,0.f,0.f,0.f};

  // staging mapping constants (bijective thread -> (n, ip, kp))
  const int kp  = l & 1;
  const int ipL = (l >> 1) & 3;
  const int nS  = ((l >> 3) & 7) | ((w & 3) << 3);          // n = 0..31
  const int sS  = nS >> 4;
  const int ldst= (nS & 15);

  // P chunk DMA (one n per wave-instr, padded dest base n*1040 B) + pos chunk DMA
  // (waves 0-3; src swizzled so LDS holds [i4][n] float4s: dest f4 d=(t) -> (i4,n)=
  //  (d>>5, d&31), src = pos4[(c*32+n)*8 + i4]).
  auto ISSUE_P = [&](int c) {
    const float4* Pg = (const float4*)(proj + (size_t)c * 32 * XD * KK);
#pragma unroll
    for (int r2 = 0; r2 < 4; ++r2) {
      const int nd = w + r2*8;
      gload16(Pg + nd*64 + l, &rawP[nd*260]);
    }
    if (t < 256) {
      const float4* Sg = (const float4*)pos;
      gload16(Sg + ((size_t)(c*32 + (t & 31)) * 8 + (t >> 5)),
              &rawPos[(t >> 6) * 256]);
    }
  };

  ISSUE_P(cbeg);
  for (int c = cbeg; c < cend; ++c) {
    __syncthreads();                           // rawP/rawPos[c] arrived; sPb free
    // ---- stage chunk c ----
    // issue color (row-gather) + sig loads first; latency hides under the P-split
    const int yq = w*8 + (l>>3);               // y = 0..63
    const int nq = (l&7)*4;
    const float* cb = colr + (size_t)(c*32 + nq)*YD + yq;
    float c0 = cb[0], c1 = cb[YD], c2 = cb[2*YD], c3 = cb[3*YD];
    float sgv = 0.f;
    if (t < 256) sgv = sig[(size_t)c * 256 + t];
    { // P 2-way split from padded rawP -> sPb[ks][l_dst][...] (all bank-uniform)
      const float4* raw4 = (const float4*)rawP;
#pragma unroll
      for (int r = 0; r < 2; ++r) {
        const int ip = ipL | (((w >> 2) & 1) << 2) | (r << 3);   // 0..15; i0 = 2*ip
        const int f0 = nS * 65 + ip * 4 + kp;
        float4 va = raw4[f0], vb = raw4[f0 + 2];
        const int l_dst = ldst | ((ip >> 2) << 4);
        const int wd = ip & 3;
        float ea[4] = {va.x, va.y, va.z, va.w};
        float eb[4] = {vb.x, vb.y, vb.z, vb.w};
#pragma unroll
        for (int jj = 0; jj < 4; ++jj) {
          const int ks = (kp*4 + jj)*2 + sS;
          unsigned hi, lo;
          asm("v_cvt_pk_bf16_f32 %0, %1, %2" : "=v"(hi) : "v"(ea[jj]), "v"(eb[jj]));
          float r0 = ea[jj] - __uint_as_float(hi << 16);          // exact residuals
          float r1 = eb[jj] - __uint_as_float(hi & 0xFFFF0000u);
          asm("v_cvt_pk_bf16_f32 %0, %1, %2" : "=v"(lo) : "v"(r0), "v"(r1));
          ((unsigned*)sPb0)[ks*256 + l_dst*4 + wd] = hi;
          ((unsigned*)sPb1)[ks*256 + l_dst*4 + wd] = lo;
        }
      }
    }
    { // colorT row-write: 2 cvt_pk -> one aligned b64 (~2-way banks)
      unsigned w0, w1;
      asm("v_cvt_pk_bf16_f32 %0, %1, %2" : "=v"(w0) : "v"(c0), "v"(c1));
      asm("v_cvt_pk_bf16_f32 %0, %1, %2" : "=v"(w1) : "v"(c2), "v"(c3));
      *(uint2*)&sCol[yq][nq] = make_uint2(w0, w1);
    }
    if (t < 256) {                             // posP from fp32 rawP (exact, same fmaf
      const int n = t >> 3, k = t & 7;         //  order as the old gaf_pre) + inv
      float d = 0.f;
#pragma unroll
      for (int j = 0; j < 8; ++j) {
        float p0 = rawPos[j*128 + n*4 + 0];    // pos[n][4j+0..3], [i4][n] layout
        float p1 = rawPos[j*128 + n*4 + 1];
        float p2 = rawPos[j*128 + n*4 + 2];
        float p3 = rawPos[j*128 + n*4 + 3];
        d = fmaf(p0, rawP[n*260 + (4*j+0)*8 + k], d);
        d = fmaf(p1, rawP[n*260 + (4*j+1)*8 + k], d);
        d = fmaf(p2, rawP[n*260 + (4*j+2)*8 + k], d);
        d = fmaf(p3, rawP[n*260 + (4*j+3)*8 + k], d);
      }
      sPosP[k][n] = d;
      sInv[k][n]  = -0.72134752044448169f / (sgv * sgv);
    }
    __syncthreads();                           // sPb/sPosP ready; rawP/rawPos consumed
    if (c + 1 < cend) ISSUE_P(c + 1);          // DMA next chunk under compute (0 VGPR)

    // ---- compute: screen (S^T) -> exp -> PV(K=32), all register-local ----
    __builtin_amdgcn_s_setprio(1);             // T5: favor MFMA waves vs sibling stage
#pragma unroll
    for (int kk = 0; kk < 4; ++kk) {
      const int k = k0 + kk;
      FragU gb;
      { // s = 0 half: n = lc
        short8 p0 = *(const short8*)&sPb0[(k*2+0)*512 + l*8];    // contiguous 1KB/wave
        short8 p1 = *(const short8*)&sPb1[(k*2+0)*512 + l*8];
        f32x4 S = (f32x4){0.f,0.f,0.f,0.f};
        S = __builtin_amdgcn_mfma_f32_16x16x32_bf16(p1, xf1, S, 0, 0, 0);
        S = __builtin_amdgcn_mfma_f32_16x16x32_bf16(p1, xf0, S, 0, 0, 0);
        S = __builtin_amdgcn_mfma_f32_16x16x32_bf16(p0, xf1, S, 0, 0, 0);
        S = __builtin_amdgcn_mfma_f32_16x16x32_bf16(p0, xf0, S, 0, 0, 0);
        float4 pp = *(const float4*)&sPosP[k][lg*4];
        float4 iv = *(const float4*)&sInv[k][lg*4];
        float d0 = S[0]-pp.x, d1 = S[1]-pp.y, d2 = S[2]-pp.z, d3 = S[3]-pp.w;
        float g0 = __builtin_amdgcn_exp2f(d0*d0*iv.x);
        float g1 = __builtin_amdgcn_exp2f(d1*d1*iv.y);
        float g2 = __builtin_amdgcn_exp2f(d2*d2*iv.z);
        float g3 = __builtin_amdgcn_exp2f(d3*d3*iv.w);
        asm("v_cvt_pk_bf16_f32 %0, %1, %2" : "=v"(gb.u[0]) : "v"(g0), "v"(g1));
        asm("v_cvt_pk_bf16_f32 %0, %1, %2" : "=v"(gb.u[1]) : "v"(g2), "v"(g3));
      }
      { // s = 1 half: n = 16 + lc
        short8 p0 = *(const short8*)&sPb0[(k*2+1)*512 + l*8];
        short8 p1 = *(const short8*)&sPb1[(k*2+1)*512 + l*8];
        f32x4 S = (f32x4){0.f,0.f,0.f,0.f};
        S = __builtin_amdgcn_mfma_f32_16x16x32_bf16(p1, xf1, S, 0, 0, 0);
        S = __builtin_amdgcn_mfma_f32_16x16x32_bf16(p1, xf0, S, 0, 0, 0);
        S = __builtin_amdgcn_mfma_f32_16x16x32_bf16(p0, xf1, S, 0, 0, 0);
        S = __builtin_amdgcn_mfma_f32_16x16x32_bf16(p0, xf0, S, 0, 0, 0);
        float4 pp = *(const float4*)&sPosP[k][16 + lg*4];
        float4 iv = *(const float4*)&sInv[k][16 + lg*4];
        float d0 = S[0]-pp.x, d1 = S[1]-pp.y, d2 = S[2]-pp.z, d3 = S[3]-pp.w;
        float g0 = __builtin_amdgcn_exp2f(d0*d0*iv.x);
        float g1 = __builtin_amdgcn_exp2f(d1*d1*iv.y);
        float g2 = __builtin_amdgcn_exp2f(d2*d2*iv.z);
        float g3 = __builtin_amdgcn_exp2f(d3*d3*iv.w);
        asm("v_cvt_pk_bf16_f32 %0, %1, %2" : "=v"(gb.u[2]) : "v"(g0), "v"(g1));
        asm("v_cvt_pk_bf16_f32 %0, %1, %2" : "=v"(gb.u[3]) : "v"(g2), "v"(g3));
      }
      // PV, full K=32: B slots j=0..3 <-> n=lg*4+j (s=0), j=4..7 <-> n=16+lg*4+(j-4).
      // A (color^T) uses the same K-permutation; consistent permutation cancels in MFMA.
#pragma unroll
      for (int ys = 0; ys < 4; ++ys) {
        FragU af;
        *(uint2*)&af.u[0] = *(const uint2*)&sCol[ys*16 + lc][lg*4];
        *(uint2*)&af.u[2] = *(const uint2*)&sCol[ys*16 + lc][16 + lg*4];
        acc[kk][ys] = __builtin_amdgcn_mfma_f32_16x16x32_bf16(af.s8, gb.s8,
                                                              acc[kk][ys], 0, 0, 0);
      }
    }
    __builtin_amdgcn_s_setprio(0);
  }
  __syncthreads();                             // compute done before epilogue overlay

  // ---- epilogue: transpose acc via LDS, coalesced partial write ----
  float* epi = (float*)sPool + w * (64*17);    // per-wave [64y][17] f32 (34816 B < pool)
#pragma unroll
  for (int kk = 0; kk < 4; ++kk) {
    const int k = k0 + kk;
#pragma unroll
    for (int ys = 0; ys < 4; ++ys) {
#pragma unroll
      for (int r = 0; r < 4; ++r)
        epi[(ys*16 + lg*4 + r)*17 + lc] = acc[kk][ys][r];
    }
    __syncthreads();
#pragma unroll
    for (int it = 0; it < 4; ++it) {
      int bi = it*4 + lg, y0 = lc*4;
      float4 v = { epi[(y0+0)*17 + bi], epi[(y0+1)*17 + bi],
                   epi[(y0+2)*17 + bi], epi[(y0+3)*17 + bi] };
      *(float4*)&pb[(size_t)(bt*16 + bi)*512 + k*64 + y0] = v;
    }
    __syncthreads();
  }
}

// ---------------- reduce: out = sum of NR partials ----------------
__global__ __launch_bounds__(512)
void gaf_reduce(const float* __restrict__ partial, float* __restrict__ out, int NR) {
  const int b = blockIdx.x;                    // global b
  const int s = b >> 6, bl = b & 63;
  const int t = threadIdx.x;                   // (k,y) flat 0..511
  float a0 = 0.f, a1 = 0.f, a2 = 0.f, a3 = 0.f;
  int nr = 0;
  for (; nr + 4 <= NR; nr += 4) {
    a0 += partial[(size_t)((nr+0)*4 + s)*PART_FLOATS + bl*512 + t];
    a1 += partial[(size_t)((nr+1)*4 + s)*PART_FLOATS + bl*512 + t];
    a2 += partial[(size_t)((nr+2)*4 + s)*PART_FLOATS + bl*512 + t];
    a3 += partial[(size_t)((nr+3)*4 + s)*PART_FLOATS + bl*512 + t];
  }
  for (; nr < NR; ++nr)
    a0 += partial[(size_t)(nr*4 + s)*PART_FLOATS + bl*512 + t];
  out[(size_t)b*512 + t] = (a0 + a1) + (a2 + a3);
}

extern "C" void kernel_launch(void* const* d_in, const int* in_sizes, int n_in,
                              void* d_out, int out_size, void* d_ws, size_t ws_size,
                              hipStream_t stream) {
  const float* x    = (const float*)d_in[0];
  const float* pos  = (const float*)d_in[1];
  const float* proj = (const float*)d_in[2];
  const float* colr = (const float*)d_in[3];
  const float* sig  = (const float*)d_in[4];
  float* out = (float*)d_out;

  float* partial = (float*)d_ws;

  int NR = (int)(ws_size / (4ull * PART_FLOATS * 4ull));  // 512 KB per NR step
  if (NR > 128) NR = 128;
  if (NR < 1)  NR = 1;
  if (NR >= 8) NR &= ~7;                       // multiple of 8 for the XCD swizzle
  int NCH = (NCHUNKS + NR - 1) / NR;

  gaf_main<<<4*NR, 512, 0, stream>>>(x, pos, proj, colr, sig, partial, NCH, NR);
  gaf_reduce<<<256, 512, 0, stream>>>(partial, out, NR);
}